// Round 8
// baseline (49.662 us; speedup 1.0000x reference)
//
#include <hip/hip_runtime.h>
#include <hip/hip_bf16.h>

// Problem constants (fixed by reference):
#define SS 512
#define HH 768
#define LL 32
#define DD 1536   // 2*H
#define MM 2048   // B*L rows
#define KK DD     // GEMM K

// GEMM geometry: 256 blocks (1/CU), tile 128x96, 4 waves of 64x48, BK=64
#define BM 128
#define BN 96
#define BK 64
#define NSTEP (KK / BK)   // 24

typedef float f32x4 __attribute__((ext_vector_type(4)));
typedef short bf16x8 __attribute__((ext_vector_type(8)));

__device__ __forceinline__ unsigned short f2bf(float x) {
    union { float f; unsigned u; } v; v.f = x;
    unsigned r = v.u + 0x7fff + ((v.u >> 16) & 1);   // round-to-nearest-even
    return (unsigned short)(r >> 16);
}

__device__ __forceinline__ void gload16(const unsigned short* g, unsigned short* l) {
    // async global->LDS, 16B/lane; LDS dest = wave-uniform base + lane*16
    __builtin_amdgcn_global_load_lds(
        (const __attribute__((address_space(1))) void*)g,
        (__attribute__((address_space(3))) void*)l, 16, 0, 0);
}

// ---------------------------------------------------------------------------
// Fused prep, 192 threads/block (float4 per thread):
//   blocks [0,2048)    : clause_h rows (bf16)  [mean(768) | cls(768)]
//   blocks [2048,5120) : W_pool f32->bf16
//   blocks [5120,5131) : init logits to b_out
// ---------------------------------------------------------------------------
__global__ __launch_bounds__(192)
void prep(const float* __restrict__ seq, const int* __restrict__ pos,
          const float* __restrict__ Wp, const float* __restrict__ bo,
          unsigned short* __restrict__ Abf, unsigned short* __restrict__ Wbf,
          float* __restrict__ out) {
    const int blk = blockIdx.x;
    const int tid = threadIdx.x;            // 0..191
    if (blk < MM) {
        int b = blk >> 5;
        int l = blk & 31;
        const int* pb = pos + b * (LL + 1);
        int start = pb[l] + 1;
        int end   = pb[l + 1] + 1;
        if (l == LL - 1) end += 1;          // last clause also takes the SEP
        float inv = 1.0f / (float)(end - start);
        const float* base = seq + (size_t)b * SS * HH;
        float4 a = make_float4(0.f, 0.f, 0.f, 0.f);
        for (int t = start; t < end; ++t) {
            float4 v = reinterpret_cast<const float4*>(base + (size_t)t * HH)[tid];
            a.x += v.x; a.y += v.y; a.z += v.z; a.w += v.w;
        }
        unsigned short* o = Abf + (size_t)blk * DD;
        ushort4 m;
        m.x = f2bf(a.x * inv); m.y = f2bf(a.y * inv);
        m.z = f2bf(a.z * inv); m.w = f2bf(a.w * inv);
        reinterpret_cast<ushort4*>(o)[tid] = m;
        float4 c = reinterpret_cast<const float4*>(base)[tid];   // CLS = token 0
        ushort4 cc;
        cc.x = f2bf(c.x); cc.y = f2bf(c.y); cc.z = f2bf(c.z); cc.w = f2bf(c.w);
        reinterpret_cast<ushort4*>(o + HH)[tid] = cc;
    } else if (blk < MM + 3072) {
        int i = ((blk - MM) * 192 + tid) * 4;        // DD*DD = 3072*192*4
        float4 v = *(const float4*)(Wp + i);
        ushort4 o;
        o.x = f2bf(v.x); o.y = f2bf(v.y); o.z = f2bf(v.z); o.w = f2bf(v.w);
        *(ushort4*)(Wbf + i) = o;
    } else {
        int i = (blk - MM - 3072) * 192 + tid;
        if (i < MM) out[i] = bo[0];
    }
}

// ---------------------------------------------------------------------------
// GEMM: 256 blocks (exactly 1/CU, balanced), tile 128x96, 4 waves (2x2) of
// 64x48 wave tiles (12 frags/wave -> LDS reads 0.58 KB/MFMA vs 1.0 before).
// BK=64, 2 LDS buffers (56 KB), stage-ahead-1 (7 gload_lds/wave/step),
// vmcnt(0)+barrier at top (one ~1100-cyc step of latency cover). XOR-swizzle
// via pre-swizzled source + swizzled read (verified conflict-free).
// Per-XCD chunk: 4 bm x 8 bn -> A 2.0 MB + B 2.4 MB ~ L2-resident.
// Fused epilogue: tanh(acc+b_pool)*W_out, 16-lane shfl reduce, atomicAdd.
// ---------------------------------------------------------------------------
__global__ __launch_bounds__(256, 2)
void gemm_mfma(const unsigned short* __restrict__ A,   // [MM][KK] bf16
               const unsigned short* __restrict__ Bm,  // [DD][KK] bf16
               const float* __restrict__ bp,           // [DD]
               const float* __restrict__ Wo,           // [DD]
               float* __restrict__ out) {              // [MM]
    __shared__ unsigned short As[2][BM * BK];  // 2 x 16 KB
    __shared__ unsigned short Bs[2][BN * BK];  // 2 x 12 KB  (56 KB total)
    const int tid  = threadIdx.x;
    const int wid  = tid >> 6;          // 0..3
    const int lane = tid & 63;
    const int fr   = lane & 15;
    const int fq   = lane >> 4;
    const int wr   = wid >> 1, wc = wid & 1;

    // 256 blocks: xcd = blk&7 (HW round-robin); per-XCD chunk 4 bm x 8 bn
    const int blk = blockIdx.x;             // 0..255
    const int xcd = blk & 7;
    const int ii  = blk >> 3;               // 0..31
    const int bm  = (xcd >> 1) * 4 + (ii & 3);    // 0..15
    const int bn  = (xcd & 1) * 8 + (ii >> 2);    // 0..15
    const int brow = bm * BM;
    const int bcol = bn * BN;

    // staging: each gload covers 8 rows (64 lanes x 16B = 8 x 128B rows);
    // lane l -> row +l>>3, source chunk (l&7)^(l>>3)  (pre-swizzle, rule #21)
    const int lr  = lane >> 3;              // 0..7
    const int sch = (lane & 7) ^ lr;        // swizzled source chunk
    const unsigned short* gA = A  + (size_t)(brow + wid * 32 + lr) * KK + sch * 8;
    const unsigned short* gB = Bm + (size_t)(bcol + wid * 24 + lr) * KK + sch * 8;

    // wave wid stages A rows [wid*32, +32) (4 gloads), B rows [wid*24, +24) (3)
#define STAGE(buf, t) do {                                                    \
        _Pragma("unroll")                                                     \
        for (int j = 0; j < 4; ++j)                                           \
            gload16(gA + (size_t)j * 8 * KK + (t) * 64,                       \
                    &As[buf][(wid * 32 + j * 8) * 64]);                       \
        _Pragma("unroll")                                                     \
        for (int j = 0; j < 3; ++j)                                           \
            gload16(gB + (size_t)j * 8 * KK + (t) * 64,                       \
                    &Bs[buf][(wid * 24 + j * 8) * 64]);                       \
    } while (0)

    // read slots: desired chunk (4h+fq) ^ (row&7); row&7 == fr&7 always
    const int s0 = fq ^ (fr & 7);           // k-half 0
    const int s1 = s0 ^ 4;                  // k-half 1
    int oA0[4], oA1[4], oB0[3], oB1[3];
    #pragma unroll
    for (int m = 0; m < 4; ++m) {
        int r = (wr * 64 + m * 16 + fr) * 64;
        oA0[m] = r + s0 * 8; oA1[m] = r + s1 * 8;
    }
    #pragma unroll
    for (int n = 0; n < 3; ++n) {
        int r = (wc * 48 + n * 16 + fr) * 64;
        oB0[n] = r + s0 * 8; oB1[n] = r + s1 * 8;
    }

    f32x4 acc[4][3] = {};

    STAGE(0, 0);                             // ahead-1 prologue

    #pragma unroll
    for (int t = 0; t < NSTEP; ++t) {
        const int buf = t & 1;
        __builtin_amdgcn_sched_barrier(0);
        asm volatile("s_waitcnt vmcnt(0)" ::: "memory");   // tile t ready (mine)
        __builtin_amdgcn_s_barrier();                      // everyone's ready
        __builtin_amdgcn_sched_barrier(0);
        if (t + 1 < NSTEP) STAGE(buf ^ 1, t + 1);          // overlaps this step
        const unsigned short* as_ = As[buf];
        const unsigned short* bs_ = Bs[buf];
        #pragma unroll
        for (int h = 0; h < 2; ++h) {
            bf16x8 a[4], b[3];
            #pragma unroll
            for (int m = 0; m < 4; ++m)
                a[m] = *(const bf16x8*)(as_ + (h ? oA1[m] : oA0[m]));
            #pragma unroll
            for (int n = 0; n < 3; ++n)
                b[n] = *(const bf16x8*)(bs_ + (h ? oB1[n] : oB0[n]));
            __builtin_amdgcn_s_setprio(1);
            #pragma unroll
            for (int m = 0; m < 4; ++m)
                #pragma unroll
                for (int n = 0; n < 3; ++n)
                    acc[m][n] = __builtin_amdgcn_mfma_f32_16x16x32_bf16(
                        a[m], b[n], acc[m][n], 0, 0, 0);
            __builtin_amdgcn_s_setprio(0);
        }
    }
#undef STAGE

    // epilogue: C/D layout col=lane&15, row=(lane>>4)*4+reg (m89-verified)
    #pragma unroll
    for (int m = 0; m < 4; ++m) {
        float vsum[4] = {0.f, 0.f, 0.f, 0.f};
        #pragma unroll
        for (int n = 0; n < 3; ++n) {
            const int col = bcol + wc * 48 + n * 16 + fr;
            const float wo_ = Wo[col];
            const float pb_ = bp[col];
            #pragma unroll
            for (int r = 0; r < 4; ++r) {
                float x = acc[m][n][r] + pb_;
                float th = 1.f - 2.f / (__expf(2.f * x) + 1.f);  // tanh(x)
                vsum[r] += th * wo_;
            }
        }
        #pragma unroll
        for (int r = 0; r < 4; ++r) {
            float v = vsum[r];
            v += __shfl_xor(v, 1, 16);
            v += __shfl_xor(v, 2, 16);
            v += __shfl_xor(v, 4, 16);
            v += __shfl_xor(v, 8, 16);
            if (fr == 0)
                atomicAdd(&out[brow + wr * 64 + m * 16 + fq * 4 + r], v);
        }
    }
}

// ---------------------------------------------------------------------------
extern "C" void kernel_launch(void* const* d_in, const int* in_sizes, int n_in,
                              void* d_out, int out_size, void* d_ws, size_t ws_size,
                              hipStream_t stream) {
    const float* seq   = (const float*)d_in[0];  // [B,S,H]
    // d_in[1] = context_h (unused by reference)
    const float* Wp    = (const float*)d_in[2];  // [D,D]
    const float* bp    = (const float*)d_in[3];  // [D]
    const float* Wo    = (const float*)d_in[4];  // [D]
    const float* bo    = (const float*)d_in[5];  // scalar
    const int*   pos   = (const int*)d_in[6];    // [B,L+1]
    // d_in[7] = doc_lens (unused by reference)
    float* out = (float*)d_out;                  // [B,L] = 2048

    unsigned short* Abf = (unsigned short*)d_ws;       // [MM][DD] bf16
    unsigned short* Wbf = Abf + (size_t)MM * DD;       // [DD][DD] bf16

    const int ninit = (MM + 191) / 192;                // 11
    prep<<<MM + 3072 + ninit, 192, 0, stream>>>(seq, pos, Wp, bo, Abf, Wbf, out);
    gemm_mfma<<<256, 256, 0, stream>>>(Abf, Wbf, bp, Wo, out);
}

// Round 9
// 49.125 us; speedup vs baseline: 1.0109x; 1.0109x over previous
//
#include <hip/hip_runtime.h>
#include <hip/hip_bf16.h>

// Problem constants (fixed by reference):
#define SS 512
#define HH 768
#define LL 32
#define DD 1536   // 2*H
#define MM 2048   // B*L rows
#define KK DD     // GEMM K

// GEMM geometry: tile 64x128, 2 waves (each 64x64), BK=64, 384 blocks
#define BK 64
#define NSTEP (KK / BK)   // 24

typedef float f32x4 __attribute__((ext_vector_type(4)));
typedef short bf16x8 __attribute__((ext_vector_type(8)));

__device__ __forceinline__ unsigned short f2bf(float x) {
    union { float f; unsigned u; } v; v.f = x;
    unsigned r = v.u + 0x7fff + ((v.u >> 16) & 1);   // round-to-nearest-even
    return (unsigned short)(r >> 16);
}

__device__ __forceinline__ void gload16(const unsigned short* g, unsigned short* l) {
    // async global->LDS, 16B/lane; LDS dest = wave-uniform base + lane*16
    __builtin_amdgcn_global_load_lds(
        (const __attribute__((address_space(1))) void*)g,
        (__attribute__((address_space(3))) void*)l, 16, 0, 0);
}

// ---------------------------------------------------------------------------
// Fused prep, 192 threads/block (float4 per thread):
//   blocks [0,2048)    : clause_h rows (bf16)  [mean(768) | cls(768)]
//   blocks [2048,5120) : W_pool f32->bf16
//   blocks [5120,5131) : init logits to b_out
// ---------------------------------------------------------------------------
__global__ __launch_bounds__(192)
void prep(const float* __restrict__ seq, const int* __restrict__ pos,
          const float* __restrict__ Wp, const float* __restrict__ bo,
          unsigned short* __restrict__ Abf, unsigned short* __restrict__ Wbf,
          float* __restrict__ out) {
    const int blk = blockIdx.x;
    const int tid = threadIdx.x;            // 0..191
    if (blk < MM) {
        int b = blk >> 5;
        int l = blk & 31;
        const int* pb = pos + b * (LL + 1);
        int start = pb[l] + 1;
        int end   = pb[l + 1] + 1;
        if (l == LL - 1) end += 1;          // last clause also takes the SEP
        float inv = 1.0f / (float)(end - start);
        const float* base = seq + (size_t)b * SS * HH;
        float4 a = make_float4(0.f, 0.f, 0.f, 0.f);
        for (int t = start; t < end; ++t) {
            float4 v = reinterpret_cast<const float4*>(base + (size_t)t * HH)[tid];
            a.x += v.x; a.y += v.y; a.z += v.z; a.w += v.w;
        }
        unsigned short* o = Abf + (size_t)blk * DD;
        ushort4 m;
        m.x = f2bf(a.x * inv); m.y = f2bf(a.y * inv);
        m.z = f2bf(a.z * inv); m.w = f2bf(a.w * inv);
        reinterpret_cast<ushort4*>(o)[tid] = m;
        float4 c = reinterpret_cast<const float4*>(base)[tid];   // CLS = token 0
        ushort4 cc;
        cc.x = f2bf(c.x); cc.y = f2bf(c.y); cc.z = f2bf(c.z); cc.w = f2bf(c.w);
        reinterpret_cast<ushort4*>(o + HH)[tid] = cc;
    } else if (blk < MM + 3072) {
        int i = ((blk - MM) * 192 + tid) * 4;        // DD*DD = 3072*192*4
        float4 v = *(const float4*)(Wp + i);
        ushort4 o;
        o.x = f2bf(v.x); o.y = f2bf(v.y); o.z = f2bf(v.z); o.w = f2bf(v.w);
        *(ushort4*)(Wbf + i) = o;
    } else {
        int i = (blk - MM - 3072) * 192 + tid;
        if (i < MM) out[i] = bo[0];
    }
}

// ---------------------------------------------------------------------------
// GEMM: tile 64x128, 2 waves, wave tile 64x64 (16 frags -> 0.5 KB LDS read
// per MFMA, half of the 32x32 config). BK=64, 3 LDS bufs (72 KB -> 2
// blocks/CU), ahead-2 staging with counted vmcnt(12) (one 12-load stage
// always in flight; drain only at tail). 384 blocks (avg 1.5/CU, 2 resident
// on half the CUs -> cross-block overlap, no lockstep). XOR-swizzle via
// pre-swizzled source + swizzled read (verified conflict-free R5-R8).
// Per-XCD chunk 8bm x 6bn: A 1.57 MB + B 2.36 MB < 4 MB L2.
// Fused epilogue: tanh(acc+b_pool)*W_out, 16-lane shfl reduce, atomicAdd.
// ---------------------------------------------------------------------------
__global__ __launch_bounds__(128, 2)
void gemm_mfma(const unsigned short* __restrict__ A,   // [MM][KK] bf16
               const unsigned short* __restrict__ Bm,  // [DD][KK] bf16
               const float* __restrict__ bp,           // [DD]
               const float* __restrict__ Wo,           // [DD]
               float* __restrict__ out) {              // [MM]
    __shared__ unsigned short As[3 * 4096];  // 3 bufs x 64x64  bf16 = 24 KB
    __shared__ unsigned short Bs[3 * 8192];  // 3 bufs x 128x64 bf16 = 48 KB
    const int tid  = threadIdx.x;
    const int wid  = tid >> 6;          // 0..1 (B-col half)
    const int lane = tid & 63;
    const int fr   = lane & 15;
    const int fq   = lane >> 4;

    // 384 blocks: xcd = blk&7 (HW round-robin); per-XCD chunk 8 bm x 6 bn
    const int blk = blockIdx.x;             // 0..383
    const int xcd = blk & 7;
    const int ii  = blk >> 3;               // 0..47
    const int bm  = (xcd >> 1) * 8 + (ii & 7);    // 0..31
    const int bn  = (xcd & 1) * 6 + (ii >> 3);    // 0..11
    const int brow = bm * 64;
    const int bcol = bn * 128;

    // staging: each gload covers 8 rows (64 lanes x 16B); lane l -> row
    // +l>>3, source chunk (l&7)^(l>>3) (pre-swizzle, rule #21).
    // wave w stages: A rows [w*32,+32) (4 gloads), B rows [w*64,+64) (8).
    const int lr  = lane >> 3;              // 0..7
    const int sch = (lane & 7) ^ lr;        // swizzled source chunk
    const unsigned short* gA = A  + (size_t)(brow + wid * 32 + lr) * KK + sch * 8;
    const unsigned short* gB = Bm + (size_t)(bcol + wid * 64 + lr) * KK + sch * 8;

#define STAGE(buf, t) do {                                                    \
        _Pragma("unroll")                                                     \
        for (int j = 0; j < 4; ++j)                                           \
            gload16(gA + (size_t)j * 8 * KK + (t) * 64,                       \
                    &As[(buf) * 4096 + (wid * 32 + j * 8) * 64]);             \
        _Pragma("unroll")                                                     \
        for (int j = 0; j < 8; ++j)                                           \
            gload16(gB + (size_t)j * 8 * KK + (t) * 64,                       \
                    &Bs[(buf) * 8192 + (wid * 64 + j * 8) * 64]);             \
    } while (0)

    // read slots: desired chunk (4h+fq) ^ (row&7); row&7 == fr&7 always
    const int s0 = fq ^ (fr & 7);           // k-half 0
    const int s1 = s0 ^ 4;                  // k-half 1
    int oA0[4], oA1[4], oB0[4], oB1[4];
    #pragma unroll
    for (int m = 0; m < 4; ++m) {
        int r = (m * 16 + fr) * 64;                       // A rows 0..63
        oA0[m] = r + s0 * 8; oA1[m] = r + s1 * 8;
    }
    #pragma unroll
    for (int n = 0; n < 4; ++n) {
        int r = (wid * 64 + n * 16 + fr) * 64;            // B rows (own half)
        oB0[n] = r + s0 * 8; oB1[n] = r + s1 * 8;
    }

    f32x4 acc[4][4] = {};

    STAGE(0, 0); STAGE(1, 1);               // ahead-2 prologue (24 loads/wave)

#define BODY(t, buf) do {                                                     \
        __builtin_amdgcn_sched_barrier(0);                                    \
        if ((t) < NSTEP - 1) asm volatile("s_waitcnt vmcnt(12)" ::: "memory");\
        else                 asm volatile("s_waitcnt vmcnt(0)"  ::: "memory");\
        __builtin_amdgcn_s_barrier();                                         \
        __builtin_amdgcn_sched_barrier(0);                                    \
        if ((t) + 2 < NSTEP) STAGE(((t) + 2) % 3, (t) + 2);                   \
        const unsigned short* as_ = As + (buf) * 4096;                        \
        const unsigned short* bs_ = Bs + (buf) * 8192;                        \
        _Pragma("unroll")                                                     \
        for (int h = 0; h < 2; ++h) {                                         \
            bf16x8 a[4], b[4];                                                \
            _Pragma("unroll")                                                 \
            for (int m = 0; m < 4; ++m)                                       \
                a[m] = *(const bf16x8*)(as_ + (h ? oA1[m] : oA0[m]));         \
            _Pragma("unroll")                                                 \
            for (int n = 0; n < 4; ++n)                                       \
                b[n] = *(const bf16x8*)(bs_ + (h ? oB1[n] : oB0[n]));         \
            __builtin_amdgcn_s_setprio(1);                                    \
            _Pragma("unroll")                                                 \
            for (int m = 0; m < 4; ++m)                                       \
                _Pragma("unroll")                                             \
                for (int n = 0; n < 4; ++n)                                   \
                    acc[m][n] = __builtin_amdgcn_mfma_f32_16x16x32_bf16(      \
                        a[m], b[n], acc[m][n], 0, 0, 0);                      \
            __builtin_amdgcn_s_setprio(0);                                    \
        }                                                                     \
    } while (0)

    #pragma unroll
    for (int t = 0; t < NSTEP; ++t) {
        BODY(t, t % 3);                     // fully unrolled: compile-time t
    }
#undef BODY
#undef STAGE

    // epilogue: C/D layout col=lane&15, row=(lane>>4)*4+reg (m89-verified)
    #pragma unroll
    for (int m = 0; m < 4; ++m) {
        float vsum[4] = {0.f, 0.f, 0.f, 0.f};
        #pragma unroll
        for (int n = 0; n < 4; ++n) {
            const int col = bcol + wid * 64 + n * 16 + fr;
            const float wo_ = Wo[col];
            const float pb_ = bp[col];
            #pragma unroll
            for (int r = 0; r < 4; ++r) {
                float x = acc[m][n][r] + pb_;
                float th = 1.f - 2.f / (__expf(2.f * x) + 1.f);  // tanh(x)
                vsum[r] += th * wo_;
            }
        }
        #pragma unroll
        for (int r = 0; r < 4; ++r) {
            float v = vsum[r];
            v += __shfl_xor(v, 1, 16);
            v += __shfl_xor(v, 2, 16);
            v += __shfl_xor(v, 4, 16);
            v += __shfl_xor(v, 8, 16);
            if (fr == 0)
                atomicAdd(&out[brow + m * 16 + fq * 4 + r], v);
        }
    }
}

// ---------------------------------------------------------------------------
extern "C" void kernel_launch(void* const* d_in, const int* in_sizes, int n_in,
                              void* d_out, int out_size, void* d_ws, size_t ws_size,
                              hipStream_t stream) {
    const float* seq   = (const float*)d_in[0];  // [B,S,H]
    // d_in[1] = context_h (unused by reference)
    const float* Wp    = (const float*)d_in[2];  // [D,D]
    const float* bp    = (const float*)d_in[3];  // [D]
    const float* Wo    = (const float*)d_in[4];  // [D]
    const float* bo    = (const float*)d_in[5];  // scalar
    const int*   pos   = (const int*)d_in[6];    // [B,L+1]
    // d_in[7] = doc_lens (unused by reference)
    float* out = (float*)d_out;                  // [B,L] = 2048

    unsigned short* Abf = (unsigned short*)d_ws;       // [MM][DD] bf16
    unsigned short* Wbf = Abf + (size_t)MM * DD;       // [DD][DD] bf16

    const int ninit = (MM + 191) / 192;                // 11
    prep<<<MM + 3072 + ninit, 192, 0, stream>>>(seq, pos, Wp, bo, Abf, Wbf, out);
    gemm_mfma<<<384, 128, 0, stream>>>(Abf, Wbf, bp, Wo, out);
}